// Round 6
// baseline (237.543 us; speedup 1.0000x reference)
//
#include <hip/hip_runtime.h>

// GridGraph adjacency (COO) for all-active 2048x2048 rook grid.
// Output layout (float32): [vals(4N) | rows(4N) | cols(4N)], direction-major
// within each: d*N + p, d in ROOK order (down, up, right, left).
//
// R6 = R5 (4 elems/thread, plain float4 stores, contiguous wave stores) plus:
//  1. XCD band swizzle: blockIdx remapped so each XCD (assumed blockIdx%8)
//     owns a contiguous 256-row band -> w band (2 MiB) stays L2-resident,
//     cutting cross-XCD re-fetch of neighbor rows (~48 MiB -> ~18 MiB HBM).
//  2. Branch-free predicated loads: clamped addresses, always-load + select,
//     so all 5 loads issue up-front with zero divergence.

constexpr int HH = 2048;
constexpr int WW = 2048;
constexpr long long NN = (long long)HH * WW;

__global__ __launch_bounds__(256) void grid_adj_kernel(
    const float* __restrict__ w, float* __restrict__ out)
{
    // band swizzle: 4096 blocks = 8 XCD bands x 512 blocks
    const int L = (blockIdx.x & 7) * 512 + (blockIdx.x >> 3);
    const int t = L * 256 + threadIdx.x;
    const int p = t << 2;                 // first of 4 consecutive elements
    const int i = p >> 11;                // p / W
    const int j = p & (WW - 1);           // p % W (multiple of 4)

    float* __restrict__ vals = out;
    float* __restrict__ rows = out + 4 * NN;
    float* __restrict__ cols = out + 8 * NN;

    const bool has_dn = (i < HH - 1);
    const bool has_up = (i > 0);
    const bool has_rt = (j != WW - 4);    // only element k=3 depends on this
    const bool has_lf = (j != 0);         // only element k=0 depends on this

    // all loads issued up-front, branch-free (clamped to safe addresses)
    const float4 c0  = *(const float4*)(w + p);
    const float4 wdn = *(const float4*)(w + p + (has_dn ? WW : 0));
    const float4 wup = *(const float4*)(w + p - (has_up ? WW : 0));
    const float  w4  = w[p + (has_rt ? 4 : 0)];
    const float  wm1 = w[p - (has_lf ? 1 : 0)];

    const float fp = (float)p;
    const float4 pf = make_float4(fp, fp + 1.f, fp + 2.f, fp + 3.f);
    const float4 z4 = make_float4(0.f, 0.f, 0.f, 0.f);

    // ---- rows / cols (no load dependency) ----
    // d0: down
    {
        const float fq = fp + (float)WW;
        *(float4*)(rows + p) = has_dn ? pf : z4;
        *(float4*)(cols + p) = has_dn ? make_float4(fq, fq + 1.f, fq + 2.f, fq + 3.f) : z4;
    }
    // d1: up
    {
        const long long o = NN + p;
        const float fq = fp - (float)WW;
        *(float4*)(rows + o) = has_up ? pf : z4;
        *(float4*)(cols + o) = has_up ? make_float4(fq, fq + 1.f, fq + 2.f, fq + 3.f) : z4;
    }
    // d2: right
    {
        const long long o = 2 * NN + p;
        *(float4*)(rows + o) = make_float4(pf.x, pf.y, pf.z, has_rt ? pf.w : 0.f);
        *(float4*)(cols + o) = make_float4(fp + 1.f, fp + 2.f, fp + 3.f,
                                           has_rt ? fp + 4.f : 0.f);
    }
    // d3: left
    {
        const long long o = 3 * NN + p;
        *(float4*)(rows + o) = make_float4(has_lf ? fp : 0.f, pf.y, pf.z, pf.w);
        *(float4*)(cols + o) = make_float4(has_lf ? fp - 1.f : 0.f, fp, fp + 1.f, fp + 2.f);
    }

    // ---- vals (consume loads) ----
    *(float4*)(vals + p)          = has_dn ? wdn : z4;
    *(float4*)(vals + NN + p)     = has_up ? wup : z4;
    *(float4*)(vals + 2 * NN + p) = make_float4(c0.y, c0.z, c0.w, has_rt ? w4 : 0.f);
    *(float4*)(vals + 3 * NN + p) = make_float4(has_lf ? wm1 : 0.f, c0.x, c0.y, c0.z);
}

extern "C" void kernel_launch(void* const* d_in, const int* in_sizes, int n_in,
                              void* d_out, int out_size, void* d_ws, size_t ws_size,
                              hipStream_t stream) {
    // d_in[0] = activities (all-true bool, unused), d_in[1] = vertex_weights f32 [H*W]
    const float* w = (const float*)d_in[1];
    float* out = (float*)d_out;

    const int threads = 256;
    const int total_threads = (int)(NN / 4);       // 1,048,576 threads, 4 elems each
    const int blocks = total_threads / threads;    // 4096 blocks
    grid_adj_kernel<<<blocks, threads, 0, stream>>>(w, out);
}

// Round 7
// 212.049 us; speedup vs baseline: 1.1202x; 1.1202x over previous
//
#include <hip/hip_runtime.h>

// GridGraph adjacency (COO) for all-active 2048x2048 rook grid.
// Output layout (float32): [vals(4N) | rows(4N) | cols(4N)], direction-major
// within each: d*N + p, d in ROOK order (down, up, right, left).
//
// R7: exact R5 body (best so far, 213.3us); only launch config changed to
// 1024 threads/block -> each block writes 16 KiB contiguous per stream-dir
// (vs 4 KiB), better DRAM page locality, 4x fewer blocks. R6's XCD band
// swizzle reverted (regressed: spread concurrent writes over 8 distant
// bands = more open-page streams; w is L3-resident anyway).

constexpr int HH = 2048;
constexpr int WW = 2048;
constexpr long long NN = (long long)HH * WW;

__global__ __launch_bounds__(1024) void grid_adj_kernel(
    const float* __restrict__ w, float* __restrict__ out)
{
    const int t = blockIdx.x * blockDim.x + threadIdx.x;
    const int p = t << 2;                 // first of 4 consecutive elements
    const int i = p >> 11;                // p / W
    const int j = p & (WW - 1);           // p % W (multiple of 4)

    float* __restrict__ vals = out;
    float* __restrict__ rows = out + 4 * NN;
    float* __restrict__ cols = out + 8 * NN;

    const float fp = (float)p;
    const float4 pf = make_float4(fp, fp + 1.f, fp + 2.f, fp + 3.f);
    const float4 z4 = make_float4(0.f, 0.f, 0.f, 0.f);

    // center load — feeds left/right weight vectors
    const float4 c0 = *(const float4*)(w + p);

    // d = 0: down (i+1, j) — wave-uniform validity per row
    {
        float4 v = z4, r = z4, c = z4;
        if (i + 1 < HH) {
            v = *(const float4*)(w + p + WW);
            r = pf;
            const float fq = fp + (float)WW;
            c = make_float4(fq, fq + 1.f, fq + 2.f, fq + 3.f);
        }
        *(float4*)(vals + p) = v;
        *(float4*)(rows + p) = r;
        *(float4*)(cols + p) = c;
    }

    // d = 1: up (i-1, j)
    {
        float4 v = z4, r = z4, c = z4;
        if (i >= 1) {
            v = *(const float4*)(w + p - WW);
            r = pf;
            const float fq = fp - (float)WW;
            c = make_float4(fq, fq + 1.f, fq + 2.f, fq + 3.f);
        }
        const long long o = NN + p;
        *(float4*)(vals + o) = v;
        *(float4*)(rows + o) = r;
        *(float4*)(cols + o) = c;
    }

    // d = 2: right (i, j+1) — only k=3 at j==W-4 invalid
    {
        const bool lastok = (j < WW - 4);          // neighbor col j+4 exists
        float w4 = 0.f, r3 = 0.f, c3 = 0.f;
        if (lastok) {                              // also guards OOB read at p+4==N
            w4 = w[p + 4];
            r3 = fp + 3.f;
            c3 = fp + 4.f;
        }
        const long long o = 2 * NN + p;
        *(float4*)(vals + o) = make_float4(c0.y, c0.z, c0.w, w4);
        *(float4*)(rows + o) = make_float4(pf.x, pf.y, pf.z, r3);
        *(float4*)(cols + o) = make_float4(fp + 1.f, fp + 2.f, fp + 3.f, c3);
    }

    // d = 3: left (i, j-1) — only k=0 at j==0 invalid
    {
        const bool firstok = (j > 0);
        float wm1 = 0.f, r0 = 0.f, c0e = 0.f;
        if (firstok) {                             // also guards OOB read at p==0
            wm1 = w[p - 1];
            r0 = fp;
            c0e = fp - 1.f;
        }
        const long long o = 3 * NN + p;
        *(float4*)(vals + o) = make_float4(wm1, c0.x, c0.y, c0.z);
        *(float4*)(rows + o) = make_float4(r0, pf.y, pf.z, pf.w);
        *(float4*)(cols + o) = make_float4(c0e, fp, fp + 1.f, fp + 2.f);
    }
}

extern "C" void kernel_launch(void* const* d_in, const int* in_sizes, int n_in,
                              void* d_out, int out_size, void* d_ws, size_t ws_size,
                              hipStream_t stream) {
    // d_in[0] = activities (all-true bool, unused), d_in[1] = vertex_weights f32 [H*W]
    const float* w = (const float*)d_in[1];
    float* out = (float*)d_out;

    const int threads = 1024;
    const int total_threads = (int)(NN / 4);       // 1,048,576 threads, 4 elems each
    const int blocks = total_threads / threads;    // 1024 blocks
    grid_adj_kernel<<<blocks, threads, 0, stream>>>(w, out);
}